// Round 11
// baseline (189.097 us; speedup 1.0000x reference)
//
#include <hip/hip_runtime.h>

#define D      128
#define DM     64
#define DMLP   512
#define PMAX   150
#define VOC    152
#define EQT    151
#define NBATCH 65536

typedef __attribute__((ext_vector_type(8))) __bf16 bf16x8;
typedef __attribute__((ext_vector_type(4))) float  f32x4;

__device__ __forceinline__ float silu_f(float x){ return x / (1.0f + expf(-x)); }

// async global->LDS DMA, 16B per lane; LDS dest = wave-uniform base + lane*16
__device__ __forceinline__ void gl_lds16(const void* g, void* l) {
    __builtin_amdgcn_global_load_lds(
        (const __attribute__((address_space(1))) void*)g,
        (__attribute__((address_space(3))) void*)l, 16, 0, 0);
}

// ---- workspace layout (float-slot offsets) ----
#define OFF_MEMVEC 0        // 150*128 f32
#define OFF_X3BASE 19200    // 128 f32
#define OFF_KE     19328    // 152*128 f32
#define OFF_KP     38784    // 4*128 f32
#define OFF_SC     39296    // 150*624 f32
#define OFF_O0     132896   // 150*512 bf16
#define OFF_O1     171296   // 150*512 bf16
#define OFF_O2     209696   // 150*512 bf16
#define OFF_O3     248096   // 512 bf16
#define OFF_M3B    248352   // 150*128 bf16
#define OFF_W1F    257952   // 65536 bf16 frag-packed (chunk-contiguous)
#define OFF_W2F    290720   // 65536 bf16 frag-packed K-major (chunk-contiguous)
#define OFF_WUF    323488   // 20480 bf16

// ===== P1a: memvec + x3base + K tables (307 blocks x 256) ====================
__global__ void k_P1a(const float* __restrict__ tok, const float* __restrict__ pos,
                      const float* __restrict__ W_mem, const float* __restrict__ b_mem,
                      const float* __restrict__ W_sur, const float* __restrict__ b_sur,
                      const float* __restrict__ W_m2r, const float* __restrict__ b_m2r,
                      const float* __restrict__ W_K,
                      float* __restrict__ memvec, float* __restrict__ x3base,
                      float* __restrict__ KE, float* __restrict__ KP)
{
    int r = blockIdx.x, t = threadIdx.x;
    if (r < 150) {
        int p = r;
        __shared__ float sx0[D], sz[DM], sdiff[D], szu[DM], red4[4][DM], red2[2][D];
        if (t < D) sx0[t] = tok[p*D + t] + pos[t];
        __syncthreads();
        {
            int out = t & 63, seg = t >> 6, k0 = seg*32;
            float acc = 0.f;
            for (int k = 0; k < 32; k++) acc += sx0[k0+k] * W_mem[(k0+k)*DM + out];
            red4[seg][out] = acc;
        }
        __syncthreads();
        if (t < DM) sz[t] = silu_f(b_mem[t] + red4[0][t] + red4[1][t] + red4[2][t] + red4[3][t]);
        __syncthreads();
        {
            int out = t & 127, seg = t >> 7, j0 = seg*32;
            float acc = 0.f;
            for (int j = 0; j < 32; j++) acc += sz[j0+j] * W_sur[(j0+j)*D + out];
            red2[seg][out] = acc;
        }
        __syncthreads();
        if (t < D) sdiff[t] = sx0[t] - (b_sur[t] + red2[0][t] + red2[1][t]);
        __syncthreads();
        {
            int out = t & 63, seg = t >> 6, k0 = seg*32;
            float acc = 0.f;
            for (int k = 0; k < 32; k++) acc += sdiff[k0+k] * W_mem[(k0+k)*DM + out];
            red4[seg][out] = acc;
        }
        __syncthreads();
        if (t < DM) szu[t] = sz[t] + silu_f(red4[0][t] + red4[1][t] + red4[2][t] + red4[3][t]);
        __syncthreads();
        {
            int out = t & 127, seg = t >> 7, j0 = seg*32;
            float acc = 0.f;
            for (int j = 0; j < 32; j++) acc += szu[j0+j] * W_m2r[(j0+j)*D + out];
            red2[seg][out] = acc;
        }
        __syncthreads();
        if (t < D) memvec[p*D + t] = b_m2r[t] + red2[0][t] + red2[1][t];
    } else if (r == 150) {
        if (t < D) x3base[t] = tok[EQT*D + t] + pos[3*D + t];
    } else {
        int idx = r - 151;
        const float* src = (idx < 152) ? (tok + idx*D) : (pos + (idx-152)*D);
        float*       dst = (idx < 152) ? (KE + idx*D)  : (KP + (idx-152)*D);
        __shared__ float s[D], red2[2][D];
        if (t < D) s[t] = src[t];
        __syncthreads();
        {
            int out = t & 127, seg = t >> 7, h = out >> 5, kk = out & 31, d0 = seg*64;
            float acc = 0.f;
            for (int d = 0; d < 64; d++) acc += s[d0+d] * W_K[h*4096 + (d0+d)*32 + kk];
            red2[seg][out] = acc;
        }
        __syncthreads();
        if (t < D) dst[t] = red2[0][t] + red2[1][t];
    }
}

// ===== P2x: SC/M3B (blocks 0-299) + O-tables + weight repack (blocks 300-824)
__global__ void k_P2x(const float* __restrict__ memvec, const float* __restrict__ x3base,
                      const float* __restrict__ W_Q, const float* __restrict__ W_V,
                      const float* __restrict__ W_O,
                      const float* __restrict__ KE, const float* __restrict__ KP,
                      const float* __restrict__ tok, const float* __restrict__ pos,
                      const float* __restrict__ W1, const float* __restrict__ W2,
                      const float* __restrict__ WU,
                      float* __restrict__ SC, __bf16* __restrict__ M3B,
                      __bf16* __restrict__ O0, __bf16* __restrict__ O1,
                      __bf16* __restrict__ O2, __bf16* __restrict__ O3,
                      __bf16* __restrict__ W1f, __bf16* __restrict__ W2f, __bf16* __restrict__ WUf)
{
    int r = blockIdx.x, t = threadIdx.x;
    if (r < 300) {
        int p = r >> 1, half = r & 1;
        __shared__ float sMem[D], sIn[D], sQ3[D], sMV[D], redM[2][D];
        if (t < D) { float m = memvec[p*D + t]; sMem[t] = m; sIn[t] = m + x3base[t]; }
        __syncthreads();
        if (t < D) {
            int h = t >> 5, k = t & 31;
            float acc = 0.f;
            for (int d = 0; d < D; d++) acc += sIn[d] * W_Q[h*4096 + d*32 + k];
            sQ3[t] = acc;
        } else {
            int c = t - D; int h = c >> 5, k = c & 31;
            float acc = 0.f;
            for (int d = 0; d < D; d++) acc += sMem[d] * W_V[h*4096 + d*32 + k];
            sMV[c] = acc;
        }
        __syncthreads();
        const float scale = 0.17677669529663687f;
        for (int ii = t; ii < 312; ii += 256) {
            int i = half*312 + ii;
            int v = i >> 2, h = i & 3;
            const float4* qh = (const float4*)(sQ3 + h*32);
            float4 s4 = {0.f, 0.f, 0.f, 0.f};
            if (v < 152) {
                const float4* ke = (const float4*)(KE + v*D + h*32);
                #pragma unroll
                for (int k = 0; k < 8; k++) {
                    float4 q = qh[k], e = ke[k];
                    s4.x += q.x*e.x; s4.y += q.y*e.y; s4.z += q.z*e.z; s4.w += q.w*e.w;
                }
            } else if (v == 152 || v == 153) {
                const float4* ke = (const float4*)(KE + ((v==152)? p : EQT)*D + h*32);
                const float4* kp = (const float4*)(KP + ((v==152)? 0 : 3)*D + h*32);
                #pragma unroll
                for (int k = 0; k < 8; k++) {
                    float4 q = qh[k], e = ke[k], pp = kp[k];
                    s4.x += q.x*(e.x+pp.x); s4.y += q.y*(e.y+pp.y);
                    s4.z += q.z*(e.z+pp.z); s4.w += q.w*(e.w+pp.w);
                }
            } else {
                const float4* kp = (const float4*)(KP + ((v==154)?1:2)*D + h*32);
                #pragma unroll
                for (int k = 0; k < 8; k++) {
                    float4 q = qh[k], pp = kp[k];
                    s4.x += q.x*pp.x; s4.y += q.y*pp.y; s4.z += q.z*pp.z; s4.w += q.w*pp.w;
                }
            }
            SC[p*624 + i] = (s4.x + s4.y + s4.z + s4.w) * scale;
        }
        if (half == 0) {
            {
                int out = t & 127, seg = t >> 7, c0 = seg*64;
                float acc = 0.f;
                for (int c = 0; c < 64; c++) acc += sMV[c0+c] * W_O[(c0+c)*D + out];
                redM[seg][out] = acc;
            }
            __syncthreads();
            if (t < D) M3B[p*D + t] = (__bf16)(sIn[t] + redM[0][t] + redM[1][t]);
        }
        return;
    }
    int rr = r - 300;
    if (rr < 451) {
        int idx = rr;
        int tt, v; __bf16* outp;
        if (idx < 150)      { tt = 0; v = idx;       outp = O0 + v*512; }
        else if (idx < 300) { tt = 1; v = idx - 150; outp = O1 + (idx-150)*512; }
        else if (idx < 450) { tt = 2; v = idx - 300; outp = O2 + (idx-300)*512; }
        else                { tt = 3; v = EQT;       outp = O3; }
        __shared__ float sTP[D], sv[D], red2[2][D];
        if (t < D) sTP[t] = tok[v*D + t] + pos[tt*D + t];
        __syncthreads();
        {
            int out = t & 127, seg = t >> 7, h = out >> 5, kk = out & 31, d0 = seg*64;
            float acc = 0.f;
            for (int d = 0; d < 64; d++) acc += sTP[d0+d] * W_V[h*4096 + (d0+d)*32 + kk];
            red2[seg][out] = acc;
        }
        __syncthreads();
        if (t < D) sv[t] = red2[0][t] + red2[1][t];
        __syncthreads();
        #pragma unroll
        for (int i = 0; i < 2; i++) {
            int c = t + i*256;
            int h = c >> 7, m = c & 127;
            float acc = 0.f;
            for (int k = 0; k < 32; k++) acc += sv[h*32 + k] * W_O[h*4096 + k*128 + m];
            outp[c] = (__bf16)acc;
        }
    } else if (rr < 483) {
        int f = (rr-451)*256 + t;                      // W1 128x512, f=(nbg*4+kb)*64+l
        int l = f & 63, kb = (f>>6) & 3, nb = f >> 8;
        int k0 = kb*32 + (l>>4)*8, n = nb*16 + (l&15);
        #pragma unroll
        for (int j = 0; j < 8; j++) W1f[f*8 + j] = (__bf16)W1[(k0+j)*DMLP + n];
    } else if (rr < 515) {
        int f = (rr-483)*256 + t;                      // W2 512x128, K-MAJOR: f=(kb*8+nb)*64+l
        int l = f & 63, g = f >> 6;
        int nb = g & 7, kb = g >> 3;
        int k0 = kb*32 + (l>>4)*8, n = nb*16 + (l&15);
        #pragma unroll
        for (int j = 0; j < 8; j++) W2f[f*8 + j] = (__bf16)W2[(k0+j)*D + n];
    } else {
        int f = (rr-515)*256 + t;                      // W_un 128x150 (N pad 160), f=(nt*4+kb)*64+l
        int l = f & 63, kb = (f>>6) & 3, nb = f >> 8;
        int k0 = kb*32 + (l>>4)*8, n = nb*16 + (l&15);
        #pragma unroll
        for (int j = 0; j < 8; j++) WUf[f*8 + j] = (__bf16)((n < 150) ? WU[(k0+j)*150 + n] : 0.f);
    }
}

// ===== FUSED v9: R10 base + H software-pipelined by one chunk ===============
// 1024 blocks x 256 thr (4 waves), 16 rows/wave, 4 blocks/CU.
// vs R10: iteration cc computes MLP1(cc) AND MLP2(cc-1). The previous H is
// read from the panel at iteration top (same-wave DS pipe order + a
// compile-time sched_barrier pins read-before-overwrite; cross-iteration RAW
// is ordered by the end-of-chunk __syncthreads). This removes the per-chunk
// lgkmcnt(0) fence that serialized [W1-reads -> MFMA -> panel-write || STALL
// || panel-read -> W2-reads -> MFMA] per wave — R10's counters (LDS~45% +
// VALU 33% + MFMA 13% ~ sum 91%) showed the pipes running serialized.
// W2 staging shifts one iter later than W1 (prefetch W2(cc) during iter cc,
// consume at iter cc+1); dbuf parity: W1(cc)@buf[cc&1], W2(cc)@buf[cc&1].
// LDS (39936 B <= 40960 -> 4 blk/CU):
//   [0,8192)       W1 buf0   | [8192,16384)  W1 buf1
//   [16384,24576)  W2 buf0   | [24576,32768) W2 buf1
//   [8192,24576)   phase-A x3 panel — overlays W1b1+W2b0, both staged only
//                  AFTER the post-A barrier (iter-0 prefetch)
//   [32768,37888)  H panels, 1280 B/wave (16 x 40 bf16)
//   [37888,39936)  sB1 (512 f32)
//   [0,16384)      epilogue x'' panel | [16384,32768) WU staging passes
__global__ __launch_bounds__(256, 4) void k_fused(
    const int* __restrict__ p_val, const int* __restrict__ a_tok, const int* __restrict__ b_tok,
    const float* __restrict__ SC, const __bf16* __restrict__ O0, const __bf16* __restrict__ O1,
    const __bf16* __restrict__ O2, const __bf16* __restrict__ O3g, const __bf16* __restrict__ M3B,
    const __bf16* __restrict__ W1f, const __bf16* __restrict__ W2f, const __bf16* __restrict__ WUf,
    const float* __restrict__ b1, const float* __restrict__ b2, const float* __restrict__ bun,
    float* __restrict__ out)
{
    __shared__ __align__(16) char smem[39936];
    char*  sX3 = smem + 8192;              // x3 panel, 64 x 256 B, phase A only
    float* sB1 = (float*)(smem + 37888);

    int tid = threadIdx.x;
    int wv = tid >> 6, l = tid & 63, lr = l & 15, quad = l >> 4;
    int tbase = blockIdx.x * 64 + wv * 16;

    const char* gW1 = (const char*)W1f;
    const char* gW2 = (const char*)W2f;

    // W1 chunk-0 async staging issued FIRST — in flight during phase A
    gl_lds16(gW1 + tid*16,       smem + tid*16);            // W1 buf0
    gl_lds16(gW1 + (tid+256)*16, smem + (tid+256)*16);
    sB1[tid] = b1[tid]; sB1[tid+256] = b1[tid+256];

    // ---------- phase A: attention; wave-private 16 rows ----------
    {
        int s = tid >> 2, h = tid & 3;
        int gs = blockIdx.x * 64 + s;
        int p = p_val[gs], ta = a_tok[gs], tb = b_tok[gs];

        float wloc[4];
        {
            const float* SCp = SC + p*624;
            float sc0 = SCp[608 + h];
            float sc3 = SCp[612 + h];
            float sc1 = SCp[ta*4 + h] + SCp[616 + h];
            float sc2 = SCp[tb*4 + h] + SCp[620 + h];
            float mx = fmaxf(fmaxf(sc0, sc1), fmaxf(sc2, sc3));
            float e0 = expf(sc0-mx), e1 = expf(sc1-mx), e2 = expf(sc2-mx), e3 = expf(sc3-mx);
            float inv = 1.f / (e0 + e1 + e2 + e3);
            wloc[0] = e0*inv; wloc[1] = e1*inv; wloc[2] = e2*inv; wloc[3] = e3*inv;
        }
        float w[16];
        #pragma unroll
        for (int j = 0; j < 4; j++) w[h*4 + j] = wloc[j];
        #pragma unroll
        for (int m = 1; m < 4; m++) {
            int oh = h ^ m;
            #pragma unroll
            for (int j = 0; j < 4; j++) w[oh*4 + j] = __shfl_xor(wloc[j], m);
        }

        const bf16x8* m3v = (const bf16x8*)(M3B + p*128);
        const bf16x8* t0  = (const bf16x8*)(O0 + p*512);
        const bf16x8* t1  = (const bf16x8*)(O1 + ta*512);
        const bf16x8* t2  = (const bf16x8*)(O2 + tb*512);
        const bf16x8* t3  = (const bf16x8*)O3g;
        #pragma unroll
        for (int jj = 0; jj < 4; jj++) {
            int c8 = h*4 + jj;
            bf16x8 mv = m3v[c8];
            float v[8];
            #pragma unroll
            for (int e = 0; e < 8; e++) v[e] = (float)mv[e];
            #pragma unroll
            for (int hh = 0; hh < 4; hh++) {
                int o8 = hh*16 + c8;
                bf16x8 e0 = t0[o8], e1 = t1[o8], e2 = t2[o8], e3 = t3[o8];
                float w0 = w[hh*4+0], w1 = w[hh*4+1], w2 = w[hh*4+2], w3 = w[hh*4+3];
                #pragma unroll
                for (int e = 0; e < 8; e++)
                    v[e] += w0*(float)e0[e] + w1*(float)e1[e] + w2*(float)e2[e] + w3*(float)e3[e];
            }
            bf16x8 st;
            #pragma unroll
            for (int e = 0; e < 8; e++) st[e] = (__bf16)v[e];
            *(bf16x8*)(sX3 + s*256 + ((c8*16) ^ ((s&7)<<4))) = st;
        }
    }
    asm volatile("s_waitcnt lgkmcnt(0)" ::: "memory");
    __builtin_amdgcn_sched_barrier(0);

    // A-fragments from wave-private rows (same-wave write->read, lgkm-ordered)
    bf16x8 a[4];
    {
        int arow = wv*16 + lr;                         // arow&7 == lr&7
        #pragma unroll
        for (int kb = 0; kb < 4; kb++)
            a[kb] = *(const bf16x8*)(sX3 + arow*256 + ((kb*64 + quad*16) ^ ((lr&7)<<4)));
    }
    __syncthreads();   // drains vmcnt (W1c0 staged); x3 consumed by all

    char* sPanH = smem + 32768 + wv*1280;  // H panel: 16 x 40 bf16, wave-private

    f32x4 acc2[8];
    #pragma unroll
    for (int i = 0; i < 8; i++) acc2[i] = (f32x4){0.f, 0.f, 0.f, 0.f};

    // ---- iter 0: MLP1(0) only; prefetch W1(1)->buf1, W2(0)->buf0 (x3 dead)
    {
        const char* g1 = gW1 + 8192;
        gl_lds16(g1 + tid*16,       smem + 8192 + tid*16);
        gl_lds16(g1 + (tid+256)*16, smem + 8192 + (tid+256)*16);
        gl_lds16(gW2 + tid*16,       smem + 16384 + tid*16);
        gl_lds16(gW2 + (tid+256)*16, smem + 16384 + (tid+256)*16);
        #pragma unroll
        for (int nbl = 0; nbl < 2; nbl++) {
            float bv = sB1[nbl*16 + lr];
            f32x4 acc = (f32x4){bv, bv, bv, bv};
            #pragma unroll
            for (int kb = 0; kb < 4; kb++) {
                bf16x8 w1 = *(const bf16x8*)(smem + ((nbl*4 + kb)*64 + l)*16);
                acc = __builtin_amdgcn_mfma_f32_16x16x32_bf16(a[kb], w1, acc, 0, 0, 0);
            }
            #pragma unroll
            for (int r = 0; r < 4; r++)
                *(__bf16*)(sPanH + (((quad*4 + r)*40) + nbl*16 + lr)*2) = (__bf16)fmaxf(acc[r], 0.f);
        }
        __syncthreads();   // drains vmcnt: W1(1)+W2(0) staged; H(0) written
    }

    // ---- steady state cc = 1..15: MLP1(cc) + MLP2(cc-1), no mid fence ----
    for (int cc = 1; cc < 16; cc++) {
        if (cc < 15) {      // prefetch W1(cc+1)
            const char* g1 = gW1 + (cc+1)*8192;
            char* d1 = smem + ((cc+1)&1)*8192;
            gl_lds16(g1 + tid*16,       d1 + tid*16);
            gl_lds16(g1 + (tid+256)*16, d1 + (tid+256)*16);
        }
        {                   // prefetch W2(cc) (consumed next iter)
            const char* g2 = gW2 + cc*8192;
            char* d2 = smem + 16384 + (cc&1)*8192;
            gl_lds16(g2 + tid*16,       d2 + tid*16);
            gl_lds16(g2 + (tid+256)*16, d2 + (tid+256)*16);
        }
        // read previous chunk's H BEFORE MLP1 overwrites the panel (DS pipe
        // order per wave; sched_barrier pins against compiler reordering)
        bf16x8 hprev = *(const bf16x8*)(sPanH + (lr*40 + quad*8)*2);
        __builtin_amdgcn_sched_barrier(0);
        // MLP1(cc)
        {
            char* w1b = smem + (cc&1)*8192;
            #pragma unroll
            for (int nbl = 0; nbl < 2; nbl++) {
                float bv = sB1[cc*32 + nbl*16 + lr];
                f32x4 acc = (f32x4){bv, bv, bv, bv};
                #pragma unroll
                for (int kb = 0; kb < 4; kb++) {
                    bf16x8 w1 = *(const bf16x8*)(w1b + ((nbl*4 + kb)*64 + l)*16);
                    acc = __builtin_amdgcn_mfma_f32_16x16x32_bf16(a[kb], w1, acc, 0, 0, 0);
                }
                #pragma unroll
                for (int r = 0; r < 4; r++)
                    *(__bf16*)(sPanH + (((quad*4 + r)*40) + nbl*16 + lr)*2) = (__bf16)fmaxf(acc[r], 0.f);
            }
        }
        // MLP2(cc-1) — W2(cc-1) from buf[(cc-1)&1], staged & barrier-crossed
        {
            char* w2b = smem + 16384 + ((cc-1)&1)*8192;
            #pragma unroll
            for (int nb2 = 0; nb2 < 8; nb2++) {
                bf16x8 w2 = *(const bf16x8*)(w2b + (nb2*64 + l)*16);
                acc2[nb2] = __builtin_amdgcn_mfma_f32_16x16x32_bf16(hprev, w2, acc2[nb2], 0, 0, 0);
            }
        }
        __syncthreads();   // drains vmcnt -> prefetches staged; orders H RAW
    }

    // ---- iter 16: MLP2(15) only — W2(15) in buf1, H(15) in panel ----
    {
        bf16x8 hprev = *(const bf16x8*)(sPanH + (lr*40 + quad*8)*2);
        char* w2b = smem + 16384 + 8192;
        #pragma unroll
        for (int nb2 = 0; nb2 < 8; nb2++) {
            bf16x8 w2 = *(const bf16x8*)(w2b + (nb2*64 + l)*16);
            acc2[nb2] = __builtin_amdgcn_mfma_f32_16x16x32_bf16(hprev, w2, acc2[nb2], 0, 0, 0);
        }
        __syncthreads();   // all waves done with W2 bufs (WU staging reuses them)
    }

    // preload epilogue/unembed biases into registers BEFORE issuing WU gl_lds
    // (younger scalar loads would force in-order retire of the prefetch)
    float rb2[8], rbun[10];
    #pragma unroll
    for (int nb2 = 0; nb2 < 8; nb2++) rb2[nb2] = b2[nb2*16 + lr];
    #pragma unroll
    for (int nt = 0; nt < 10; nt++) {
        int n = nt*16 + lr;
        rbun[nt] = (n < 150) ? bun[n] : 0.f;
    }

    // WU pass-0 prefetch into [16384,32768) — hides under residual + epilogue
    const char* gWU = (const char*)WUf;
    char* sWU = smem + 16384;
    gl_lds16(gWU + tid*16,       sWU + tid*16);
    gl_lds16(gWU + (tid+256)*16, sWU + (tid+256)*16);
    gl_lds16(gWU + (tid+512)*16, sWU + (tid+512)*16);
    gl_lds16(gWU + (tid+768)*16, sWU + (tid+768)*16);

    // residual via identity-matrix MFMA
    #pragma unroll
    for (int nb2 = 0; nb2 < 8; nb2++) {
        int kb = nb2 >> 1;
        bf16x8 bi;
        #pragma unroll
        for (int j = 0; j < 8; j++)
            bi[j] = (kb*32 + quad*8 + j == nb2*16 + lr) ? (__bf16)1.0f : (__bf16)0.0f;
        acc2[nb2] = __builtin_amdgcn_mfma_f32_16x16x32_bf16(a[kb], bi, acc2[nb2], 0, 0, 0);
    }

    // x'' = acc2 + b2 -> swizzled epilogue panel at [0,16384), wave-private rows
    #pragma unroll
    for (int nb2 = 0; nb2 < 8; nb2++) {
        int n = nb2*16 + lr;
        float bv = rb2[nb2];
        #pragma unroll
        for (int r = 0; r < 4; r++) {
            float v = acc2[nb2][r] + bv;
            int row = wv*16 + quad*4 + r;
            *(__bf16*)(smem + row*256 + ((n*2) ^ ((row&7)<<4))) = (__bf16)v;
        }
    }
    asm volatile("s_waitcnt lgkmcnt(0)" ::: "memory");
    __builtin_amdgcn_sched_barrier(0);
    bf16x8 au[4];
    {
        int arow = wv*16 + lr;
        #pragma unroll
        for (int kb = 0; kb < 4; kb++)
            au[kb] = *(const bf16x8*)(smem + arow*256 + ((kb*64 + quad*16) ^ ((lr&7)<<4)));
    }

    // unembed: WU through [16384,32768) in 3 passes (nt 0-3, 4-7, 8-9)
    #pragma unroll
    for (int q = 0; q < 3; q++) {
        if (q == 1) {
            __syncthreads();               // pass-0 fully read by all waves
            const char* g = gWU + 16384;
            gl_lds16(g + tid*16,       sWU + tid*16);
            gl_lds16(g + (tid+256)*16, sWU + (tid+256)*16);
            gl_lds16(g + (tid+512)*16, sWU + (tid+512)*16);
            gl_lds16(g + (tid+768)*16, sWU + (tid+768)*16);
        } else if (q == 2) {
            __syncthreads();               // pass-1 fully read
            const char* g = gWU + 32768;
            gl_lds16(g + tid*16,       sWU + tid*16);
            gl_lds16(g + (tid+256)*16, sWU + (tid+256)*16);
        }
        __syncthreads();                   // drains vmcnt -> pass staged
        int ntn = (q < 2) ? 4 : 2;
        #pragma unroll
        for (int ntl = 0; ntl < ntn; ntl++) {
            int nt = q*4 + ntl;
            int n = nt*16 + lr;
            f32x4 acc = (f32x4){rbun[nt], rbun[nt], rbun[nt], rbun[nt]};
            #pragma unroll
            for (int kb = 0; kb < 4; kb++) {
                bf16x8 wu = *(const bf16x8*)(sWU + ((ntl*4 + kb)*64 + l)*16);
                acc = __builtin_amdgcn_mfma_f32_16x16x32_bf16(au[kb], wu, acc, 0, 0, 0);
            }
            if (n < 150) {
                #pragma unroll
                for (int r = 0; r < 4; r++) {
                    int rowg = tbase + quad*4 + r;
                    out[rowg*150 + n] = acc[r];
                }
            }
        }
    }
}

// ============================ launcher ======================================
extern "C" void kernel_launch(void* const* d_in, const int* in_sizes, int n_in,
                              void* d_out, int out_size, void* d_ws, size_t ws_size,
                              hipStream_t stream) {
    const int*   p_val = (const int*)d_in[0];
    const int*   a_tok = (const int*)d_in[1];
    const int*   b_tok = (const int*)d_in[2];
    const float* tok   = (const float*)d_in[3];
    const float* pos   = (const float*)d_in[4];
    const float* W_mem = (const float*)d_in[5];
    const float* b_mem = (const float*)d_in[6];
    const float* W_sur = (const float*)d_in[7];
    const float* b_sur = (const float*)d_in[8];
    const float* W_m2r = (const float*)d_in[9];
    const float* b_m2r = (const float*)d_in[10];
    const float* W_Q   = (const float*)d_in[11];
    const float* W_K   = (const float*)d_in[12];
    const float* W_V   = (const float*)d_in[13];
    const float* W_O   = (const float*)d_in[14];
    const float* W1    = (const float*)d_in[15];
    const float* b1    = (const float*)d_in[16];
    const float* W2    = (const float*)d_in[17];
    const float* b2    = (const float*)d_in[18];
    const float* WU    = (const float*)d_in[19];
    const float* bun   = (const float*)d_in[20];
    float* out = (float*)d_out;

    float* ws = (float*)d_ws;
    float* memvec = ws + OFF_MEMVEC;
    float* x3base = ws + OFF_X3BASE;
    float* KE     = ws + OFF_KE;
    float* KP     = ws + OFF_KP;
    float* SC     = ws + OFF_SC;
    __bf16* O0    = (__bf16*)(ws + OFF_O0);
    __bf16* O1    = (__bf16*)(ws + OFF_O1);
    __bf16* O2    = (__bf16*)(ws + OFF_O2);
    __bf16* O3    = (__bf16*)(ws + OFF_O3);
    __bf16* M3B   = (__bf16*)(ws + OFF_M3B);
    __bf16* W1f   = (__bf16*)(ws + OFF_W1F);
    __bf16* W2f   = (__bf16*)(ws + OFF_W2F);
    __bf16* WUf   = (__bf16*)(ws + OFF_WUF);

    k_P1a<<<307, 256, 0, stream>>>(tok, pos, W_mem, b_mem, W_sur, b_sur, W_m2r, b_m2r,
                                   W_K, memvec, x3base, KE, KP);
    k_P2x<<<825, 256, 0, stream>>>(memvec, x3base, W_Q, W_V, W_O, KE, KP,
                                   tok, pos, W1, W2, WU,
                                   SC, M3B, O0, O1, O2, O3, W1f, W2f, WUf);
    k_fused<<<NBATCH/64, 256, 0, stream>>>(p_val, a_tok, b_tok, SC, O0, O1, O2, O3, M3B,
                                           W1f, W2f, WUf, b1, b2, bun, out);
}

// Round 12
// 171.366 us; speedup vs baseline: 1.1035x; 1.1035x over previous
//
#include <hip/hip_runtime.h>

#define D      128
#define DM     64
#define DMLP   512
#define PMAX   150
#define VOC    152
#define EQT    151
#define NBATCH 65536

typedef __attribute__((ext_vector_type(8))) __bf16 bf16x8;
typedef __attribute__((ext_vector_type(4))) float  f32x4;

__device__ __forceinline__ float silu_f(float x){ return x / (1.0f + expf(-x)); }

// async global->LDS DMA, 16B per lane; LDS dest = wave-uniform base + lane*16
__device__ __forceinline__ void gl_lds16(const void* g, void* l) {
    __builtin_amdgcn_global_load_lds(
        (const __attribute__((address_space(1))) void*)g,
        (__attribute__((address_space(3))) void*)l, 16, 0, 0);
}

// ---- workspace layout (float-slot offsets) ----
#define OFF_MEMVEC 0        // 150*128 f32
#define OFF_X3BASE 19200    // 128 f32
#define OFF_KE     19328    // 152*128 f32
#define OFF_KP     38784    // 4*128 f32
#define OFF_SC     39296    // 150*624 f32
#define OFF_O0     132896   // 150*512 bf16
#define OFF_O1     171296   // 150*512 bf16
#define OFF_O2     209696   // 150*512 bf16
#define OFF_O3     248096   // 512 bf16
#define OFF_M3B    248352   // 150*128 bf16
#define OFF_W1F    257952   // 65536 bf16 frag-packed (chunk-contiguous)
#define OFF_W2F    290720   // 65536 bf16 frag-packed K-major (chunk-contiguous)
#define OFF_WUF    323488   // 20480 bf16

// ===== P1a: memvec + x3base + K tables (307 blocks x 256) ====================
__global__ void k_P1a(const float* __restrict__ tok, const float* __restrict__ pos,
                      const float* __restrict__ W_mem, const float* __restrict__ b_mem,
                      const float* __restrict__ W_sur, const float* __restrict__ b_sur,
                      const float* __restrict__ W_m2r, const float* __restrict__ b_m2r,
                      const float* __restrict__ W_K,
                      float* __restrict__ memvec, float* __restrict__ x3base,
                      float* __restrict__ KE, float* __restrict__ KP)
{
    int r = blockIdx.x, t = threadIdx.x;
    if (r < 150) {
        int p = r;
        __shared__ float sx0[D], sz[DM], sdiff[D], szu[DM], red4[4][DM], red2[2][D];
        if (t < D) sx0[t] = tok[p*D + t] + pos[t];
        __syncthreads();
        {
            int out = t & 63, seg = t >> 6, k0 = seg*32;
            float acc = 0.f;
            for (int k = 0; k < 32; k++) acc += sx0[k0+k] * W_mem[(k0+k)*DM + out];
            red4[seg][out] = acc;
        }
        __syncthreads();
        if (t < DM) sz[t] = silu_f(b_mem[t] + red4[0][t] + red4[1][t] + red4[2][t] + red4[3][t]);
        __syncthreads();
        {
            int out = t & 127, seg = t >> 7, j0 = seg*32;
            float acc = 0.f;
            for (int j = 0; j < 32; j++) acc += sz[j0+j] * W_sur[(j0+j)*D + out];
            red2[seg][out] = acc;
        }
        __syncthreads();
        if (t < D) sdiff[t] = sx0[t] - (b_sur[t] + red2[0][t] + red2[1][t]);
        __syncthreads();
        {
            int out = t & 63, seg = t >> 6, k0 = seg*32;
            float acc = 0.f;
            for (int k = 0; k < 32; k++) acc += sdiff[k0+k] * W_mem[(k0+k)*DM + out];
            red4[seg][out] = acc;
        }
        __syncthreads();
        if (t < DM) szu[t] = sz[t] + silu_f(red4[0][t] + red4[1][t] + red4[2][t] + red4[3][t]);
        __syncthreads();
        {
            int out = t & 127, seg = t >> 7, j0 = seg*32;
            float acc = 0.f;
            for (int j = 0; j < 32; j++) acc += szu[j0+j] * W_m2r[(j0+j)*D + out];
            red2[seg][out] = acc;
        }
        __syncthreads();
        if (t < D) memvec[p*D + t] = b_m2r[t] + red2[0][t] + red2[1][t];
    } else if (r == 150) {
        if (t < D) x3base[t] = tok[EQT*D + t] + pos[3*D + t];
    } else {
        int idx = r - 151;
        const float* src = (idx < 152) ? (tok + idx*D) : (pos + (idx-152)*D);
        float*       dst = (idx < 152) ? (KE + idx*D)  : (KP + (idx-152)*D);
        __shared__ float s[D], red2[2][D];
        if (t < D) s[t] = src[t];
        __syncthreads();
        {
            int out = t & 127, seg = t >> 7, h = out >> 5, kk = out & 31, d0 = seg*64;
            float acc = 0.f;
            for (int d = 0; d < 64; d++) acc += s[d0+d] * W_K[h*4096 + (d0+d)*32 + kk];
            red2[seg][out] = acc;
        }
        __syncthreads();
        if (t < D) dst[t] = red2[0][t] + red2[1][t];
    }
}

// ===== P2x: SC/M3B (blocks 0-299) + O-tables + weight repack (blocks 300-824)
__global__ void k_P2x(const float* __restrict__ memvec, const float* __restrict__ x3base,
                      const float* __restrict__ W_Q, const float* __restrict__ W_V,
                      const float* __restrict__ W_O,
                      const float* __restrict__ KE, const float* __restrict__ KP,
                      const float* __restrict__ tok, const float* __restrict__ pos,
                      const float* __restrict__ W1, const float* __restrict__ W2,
                      const float* __restrict__ WU,
                      float* __restrict__ SC, __bf16* __restrict__ M3B,
                      __bf16* __restrict__ O0, __bf16* __restrict__ O1,
                      __bf16* __restrict__ O2, __bf16* __restrict__ O3,
                      __bf16* __restrict__ W1f, __bf16* __restrict__ W2f, __bf16* __restrict__ WUf)
{
    int r = blockIdx.x, t = threadIdx.x;
    if (r < 300) {
        int p = r >> 1, half = r & 1;
        __shared__ float sMem[D], sIn[D], sQ3[D], sMV[D], redM[2][D];
        if (t < D) { float m = memvec[p*D + t]; sMem[t] = m; sIn[t] = m + x3base[t]; }
        __syncthreads();
        if (t < D) {
            int h = t >> 5, k = t & 31;
            float acc = 0.f;
            for (int d = 0; d < D; d++) acc += sIn[d] * W_Q[h*4096 + d*32 + k];
            sQ3[t] = acc;
        } else {
            int c = t - D; int h = c >> 5, k = c & 31;
            float acc = 0.f;
            for (int d = 0; d < D; d++) acc += sMem[d] * W_V[h*4096 + d*32 + k];
            sMV[c] = acc;
        }
        __syncthreads();
        const float scale = 0.17677669529663687f;
        for (int ii = t; ii < 312; ii += 256) {
            int i = half*312 + ii;
            int v = i >> 2, h = i & 3;
            const float4* qh = (const float4*)(sQ3 + h*32);
            float4 s4 = {0.f, 0.f, 0.f, 0.f};
            if (v < 152) {
                const float4* ke = (const float4*)(KE + v*D + h*32);
                #pragma unroll
                for (int k = 0; k < 8; k++) {
                    float4 q = qh[k], e = ke[k];
                    s4.x += q.x*e.x; s4.y += q.y*e.y; s4.z += q.z*e.z; s4.w += q.w*e.w;
                }
            } else if (v == 152 || v == 153) {
                const float4* ke = (const float4*)(KE + ((v==152)? p : EQT)*D + h*32);
                const float4* kp = (const float4*)(KP + ((v==152)? 0 : 3)*D + h*32);
                #pragma unroll
                for (int k = 0; k < 8; k++) {
                    float4 q = qh[k], e = ke[k], pp = kp[k];
                    s4.x += q.x*(e.x+pp.x); s4.y += q.y*(e.y+pp.y);
                    s4.z += q.z*(e.z+pp.z); s4.w += q.w*(e.w+pp.w);
                }
            } else {
                const float4* kp = (const float4*)(KP + ((v==154)?1:2)*D + h*32);
                #pragma unroll
                for (int k = 0; k < 8; k++) {
                    float4 q = qh[k], pp = kp[k];
                    s4.x += q.x*pp.x; s4.y += q.y*pp.y; s4.z += q.z*pp.z; s4.w += q.w*pp.w;
                }
            }
            SC[p*624 + i] = (s4.x + s4.y + s4.z + s4.w) * scale;
        }
        if (half == 0) {
            {
                int out = t & 127, seg = t >> 7, c0 = seg*64;
                float acc = 0.f;
                for (int c = 0; c < 64; c++) acc += sMV[c0+c] * W_O[(c0+c)*D + out];
                redM[seg][out] = acc;
            }
            __syncthreads();
            if (t < D) M3B[p*D + t] = (__bf16)(sIn[t] + redM[0][t] + redM[1][t]);
        }
        return;
    }
    int rr = r - 300;
    if (rr < 451) {
        int idx = rr;
        int tt, v; __bf16* outp;
        if (idx < 150)      { tt = 0; v = idx;       outp = O0 + v*512; }
        else if (idx < 300) { tt = 1; v = idx - 150; outp = O1 + (idx-150)*512; }
        else if (idx < 450) { tt = 2; v = idx - 300; outp = O2 + (idx-300)*512; }
        else                { tt = 3; v = EQT;       outp = O3; }
        __shared__ float sTP[D], sv[D], red2[2][D];
        if (t < D) sTP[t] = tok[v*D + t] + pos[tt*D + t];
        __syncthreads();
        {
            int out = t & 127, seg = t >> 7, h = out >> 5, kk = out & 31, d0 = seg*64;
            float acc = 0.f;
            for (int d = 0; d < 64; d++) acc += sTP[d0+d] * W_V[h*4096 + (d0+d)*32 + kk];
            red2[seg][out] = acc;
        }
        __syncthreads();
        if (t < D) sv[t] = red2[0][t] + red2[1][t];
        __syncthreads();
        #pragma unroll
        for (int i = 0; i < 2; i++) {
            int c = t + i*256;
            int h = c >> 7, m = c & 127;
            float acc = 0.f;
            for (int k = 0; k < 32; k++) acc += sv[h*32 + k] * W_O[h*4096 + k*128 + m];
            outp[c] = (__bf16)acc;
        }
    } else if (rr < 483) {
        int f = (rr-451)*256 + t;                      // W1 128x512, f=(nbg*4+kb)*64+l
        int l = f & 63, kb = (f>>6) & 3, nb = f >> 8;
        int k0 = kb*32 + (l>>4)*8, n = nb*16 + (l&15);
        #pragma unroll
        for (int j = 0; j < 8; j++) W1f[f*8 + j] = (__bf16)W1[(k0+j)*DMLP + n];
    } else if (rr < 515) {
        int f = (rr-483)*256 + t;                      // W2 512x128, K-MAJOR: f=(kb*8+nb)*64+l
        int l = f & 63, g = f >> 6;
        int nb = g & 7, kb = g >> 3;
        int k0 = kb*32 + (l>>4)*8, n = nb*16 + (l&15);
        #pragma unroll
        for (int j = 0; j < 8; j++) W2f[f*8 + j] = (__bf16)W2[(k0+j)*D + n];
    } else {
        int f = (rr-515)*256 + t;                      // W_un 128x150 (N pad 160), f=(nt*4+kb)*64+l
        int l = f & 63, kb = (f>>6) & 3, nb = f >> 8;
        int k0 = kb*32 + (l>>4)*8, n = nb*16 + (l&15);
        #pragma unroll
        for (int j = 0; j < 8; j++) WUf[f*8 + j] = (__bf16)((n < 150) ? WU[(k0+j)*150 + n] : 0.f);
    }
}

// ===== FUSED v10: R10 base, lgkmcnt(0) fences dropped (same-wave DS order) ==
// 1024 blocks x 256 thr (4 waves), 16 rows/wave, 4 blocks/CU.
// vs R10 (R11's pipeline reverted — it spilled to scratch, +60MB HBM/dispatch):
// the three explicit `s_waitcnt lgkmcnt(0)` fences are removed. Every panel
// (x3, H, x'') is WAVE-PRIVATE, and LDS ops from one wave execute in order in
// the DS pipe — a ds_read issued after ds_writes to the same addresses returns
// the written data; the compiler's automatic lgkmcnt before the read's USE is
// the only wait required. A compile-time sched_barrier(0) remains at each site
// so hipcc cannot hoist the read above the writes (rule #18 alias concern).
// This removes a full-drain stall per chunk per wave at zero register cost.
// LDS (39936 B <= 40960 -> 4 blk/CU):
//   [0,8192)       W1 buf0   | [8192,16384)  W1 buf1
//   [16384,24576)  W2 buf0   | [24576,32768) W2 buf1
//   [8192,24576)   phase-A x3 panel — overlays W1b1+W2b0 (W2 c0 -> buf1)
//   [32768,37888)  H panels, 1280 B/wave (16 x 40 bf16)
//   [37888,39936)  sB1 (512 f32)
//   [0,16384)      epilogue x'' panel | [16384,32768) WU staging passes
// chunk cc: W1 in buf (cc&1), W2 in buf ((cc&1)^1).
__global__ __launch_bounds__(256, 4) void k_fused(
    const int* __restrict__ p_val, const int* __restrict__ a_tok, const int* __restrict__ b_tok,
    const float* __restrict__ SC, const __bf16* __restrict__ O0, const __bf16* __restrict__ O1,
    const __bf16* __restrict__ O2, const __bf16* __restrict__ O3g, const __bf16* __restrict__ M3B,
    const __bf16* __restrict__ W1f, const __bf16* __restrict__ W2f, const __bf16* __restrict__ WUf,
    const float* __restrict__ b1, const float* __restrict__ b2, const float* __restrict__ bun,
    float* __restrict__ out)
{
    __shared__ __align__(16) char smem[39936];
    char*  sX3 = smem + 8192;              // x3 panel, 64 x 256 B, phase A only
    float* sB1 = (float*)(smem + 37888);

    int tid = threadIdx.x;
    int wv = tid >> 6, l = tid & 63, lr = l & 15, quad = l >> 4;
    int tbase = blockIdx.x * 64 + wv * 16;

    const char* gW1 = (const char*)W1f;
    const char* gW2 = (const char*)W2f;

    // chunk-0 W1 AND W2 async staging issued FIRST — in flight during phase A
    gl_lds16(gW1 + tid*16,       smem + tid*16);            // W1 buf0
    gl_lds16(gW1 + (tid+256)*16, smem + (tid+256)*16);
    gl_lds16(gW2 + tid*16,       smem + 24576 + tid*16);    // W2 buf1
    gl_lds16(gW2 + (tid+256)*16, smem + 24576 + (tid+256)*16);
    sB1[tid] = b1[tid]; sB1[tid+256] = b1[tid+256];

    // ---------- phase A: attention; wave-private 16 rows ----------
    {
        int s = tid >> 2, h = tid & 3;
        int gs = blockIdx.x * 64 + s;
        int p = p_val[gs], ta = a_tok[gs], tb = b_tok[gs];

        float wloc[4];
        {
            const float* SCp = SC + p*624;
            float sc0 = SCp[608 + h];
            float sc3 = SCp[612 + h];
            float sc1 = SCp[ta*4 + h] + SCp[616 + h];
            float sc2 = SCp[tb*4 + h] + SCp[620 + h];
            float mx = fmaxf(fmaxf(sc0, sc1), fmaxf(sc2, sc3));
            float e0 = expf(sc0-mx), e1 = expf(sc1-mx), e2 = expf(sc2-mx), e3 = expf(sc3-mx);
            float inv = 1.f / (e0 + e1 + e2 + e3);
            wloc[0] = e0*inv; wloc[1] = e1*inv; wloc[2] = e2*inv; wloc[3] = e3*inv;
        }
        float w[16];
        #pragma unroll
        for (int j = 0; j < 4; j++) w[h*4 + j] = wloc[j];
        #pragma unroll
        for (int m = 1; m < 4; m++) {
            int oh = h ^ m;
            #pragma unroll
            for (int j = 0; j < 4; j++) w[oh*4 + j] = __shfl_xor(wloc[j], m);
        }

        const bf16x8* m3v = (const bf16x8*)(M3B + p*128);
        const bf16x8* t0  = (const bf16x8*)(O0 + p*512);
        const bf16x8* t1  = (const bf16x8*)(O1 + ta*512);
        const bf16x8* t2  = (const bf16x8*)(O2 + tb*512);
        const bf16x8* t3  = (const bf16x8*)O3g;
        #pragma unroll
        for (int jj = 0; jj < 4; jj++) {
            int c8 = h*4 + jj;
            bf16x8 mv = m3v[c8];
            float v[8];
            #pragma unroll
            for (int e = 0; e < 8; e++) v[e] = (float)mv[e];
            #pragma unroll
            for (int hh = 0; hh < 4; hh++) {
                int o8 = hh*16 + c8;
                bf16x8 e0 = t0[o8], e1 = t1[o8], e2 = t2[o8], e3 = t3[o8];
                float w0 = w[hh*4+0], w1 = w[hh*4+1], w2 = w[hh*4+2], w3 = w[hh*4+3];
                #pragma unroll
                for (int e = 0; e < 8; e++)
                    v[e] += w0*(float)e0[e] + w1*(float)e1[e] + w2*(float)e2[e] + w3*(float)e3[e];
            }
            bf16x8 st;
            #pragma unroll
            for (int e = 0; e < 8; e++) st[e] = (__bf16)v[e];
            *(bf16x8*)(sX3 + s*256 + ((c8*16) ^ ((s&7)<<4))) = st;
        }
    }
    __builtin_amdgcn_sched_barrier(0);     // pin x3 writes above a[] reads
                                           // (same-wave DS in-order; no drain)

    // A-fragments from wave-private rows
    bf16x8 a[4];
    {
        int arow = wv*16 + lr;                         // arow&7 == lr&7
        #pragma unroll
        for (int kb = 0; kb < 4; kb++)
            a[kb] = *(const bf16x8*)(sX3 + arow*256 + ((kb*64 + quad*16) ^ ((lr&7)<<4)));
    }
    __syncthreads();   // drains vmcnt (W1c0+W2c0 staged); x3 consumed by all

    char* sPanH = smem + 32768 + wv*1280;  // H panel: 16 x 40 bf16, wave-private

    f32x4 acc2[8];
    #pragma unroll
    for (int i = 0; i < 8; i++) acc2[i] = (f32x4){0.f, 0.f, 0.f, 0.f};

    for (int cc = 0; cc < 16; cc++) {
        int pb = cc & 1;
        char* w1b = smem + pb*8192;
        char* w2b = smem + 16384 + (pb^1)*8192;
        if (cc < 15) {  // async-stage next chunk into the other buffers
            const char* g1 = gW1 + (cc+1)*8192;
            const char* g2 = gW2 + (cc+1)*8192;
            char* d1 = smem + (pb^1)*8192;
            char* d2 = smem + 16384 + pb*8192;
            gl_lds16(g1 + tid*16,       d1 + tid*16);
            gl_lds16(g1 + (tid+256)*16, d1 + (tid+256)*16);
            gl_lds16(g2 + tid*16,       d2 + tid*16);
            gl_lds16(g2 + (tid+256)*16, d2 + (tid+256)*16);
        }
        // MLP1: 2 col-groups of 16 (bias from LDS — lgkm domain)
        #pragma unroll
        for (int nbl = 0; nbl < 2; nbl++) {
            float bv = sB1[cc*32 + nbl*16 + lr];
            f32x4 acc = (f32x4){bv, bv, bv, bv};
            #pragma unroll
            for (int kb = 0; kb < 4; kb++) {
                bf16x8 w1 = *(const bf16x8*)(w1b + ((nbl*4 + kb)*64 + l)*16);
                acc = __builtin_amdgcn_mfma_f32_16x16x32_bf16(a[kb], w1, acc, 0, 0, 0);
            }
            #pragma unroll
            for (int r = 0; r < 4; r++)
                *(__bf16*)(sPanH + (((quad*4 + r)*40) + nbl*16 + lr)*2) = (__bf16)fmaxf(acc[r], 0.f);
        }
        __builtin_amdgcn_sched_barrier(0); // pin H writes above H read; the DS
                                           // pipe is in-order per wave — no
                                           // full lgkmcnt(0) drain needed
        // MLP2 partial: this chunk's 32-wide K block
        {
            bf16x8 h = *(const bf16x8*)(sPanH + (lr*40 + quad*8)*2);
            #pragma unroll
            for (int nb2 = 0; nb2 < 8; nb2++) {
                bf16x8 w2 = *(const bf16x8*)(w2b + (nb2*64 + l)*16);
                acc2[nb2] = __builtin_amdgcn_mfma_f32_16x16x32_bf16(h, w2, acc2[nb2], 0, 0, 0);
            }
        }
        __syncthreads();   // drains vmcnt -> next chunk staged
    }

    // preload epilogue/unembed biases into registers BEFORE issuing WU gl_lds
    // (younger scalar loads would force in-order retire of the prefetch)
    float rb2[8], rbun[10];
    #pragma unroll
    for (int nb2 = 0; nb2 < 8; nb2++) rb2[nb2] = b2[nb2*16 + lr];
    #pragma unroll
    for (int nt = 0; nt < 10; nt++) {
        int n = nt*16 + lr;
        rbun[nt] = (n < 150) ? bun[n] : 0.f;
    }

    // WU pass-0 prefetch into [16384,32768) — hides under residual + epilogue
    const char* gWU = (const char*)WUf;
    char* sWU = smem + 16384;
    gl_lds16(gWU + tid*16,       sWU + tid*16);
    gl_lds16(gWU + (tid+256)*16, sWU + (tid+256)*16);
    gl_lds16(gWU + (tid+512)*16, sWU + (tid+512)*16);
    gl_lds16(gWU + (tid+768)*16, sWU + (tid+768)*16);

    // residual via identity-matrix MFMA
    #pragma unroll
    for (int nb2 = 0; nb2 < 8; nb2++) {
        int kb = nb2 >> 1;
        bf16x8 bi;
        #pragma unroll
        for (int j = 0; j < 8; j++)
            bi[j] = (kb*32 + quad*8 + j == nb2*16 + lr) ? (__bf16)1.0f : (__bf16)0.0f;
        acc2[nb2] = __builtin_amdgcn_mfma_f32_16x16x32_bf16(a[kb], bi, acc2[nb2], 0, 0, 0);
    }

    // x'' = acc2 + b2 -> swizzled epilogue panel at [0,16384), wave-private rows
    #pragma unroll
    for (int nb2 = 0; nb2 < 8; nb2++) {
        int n = nb2*16 + lr;
        float bv = rb2[nb2];
        #pragma unroll
        for (int r = 0; r < 4; r++) {
            float v = acc2[nb2][r] + bv;
            int row = wv*16 + quad*4 + r;
            *(__bf16*)(smem + row*256 + ((n*2) ^ ((row&7)<<4))) = (__bf16)v;
        }
    }
    __builtin_amdgcn_sched_barrier(0);     // pin x'' writes above au reads
    bf16x8 au[4];
    {
        int arow = wv*16 + lr;
        #pragma unroll
        for (int kb = 0; kb < 4; kb++)
            au[kb] = *(const bf16x8*)(smem + arow*256 + ((kb*64 + quad*16) ^ ((lr&7)<<4)));
    }

    // unembed: WU through [16384,32768) in 3 passes (nt 0-3, 4-7, 8-9)
    #pragma unroll
    for (int q = 0; q < 3; q++) {
        if (q == 1) {
            __syncthreads();               // pass-0 fully read by all waves
            const char* g = gWU + 16384;
            gl_lds16(g + tid*16,       sWU + tid*16);
            gl_lds16(g + (tid+256)*16, sWU + (tid+256)*16);
            gl_lds16(g + (tid+512)*16, sWU + (tid+512)*16);
            gl_lds16(g + (tid+768)*16, sWU + (tid+768)*16);
        } else if (q == 2) {
            __syncthreads();               // pass-1 fully read
            const char* g = gWU + 32768;
            gl_lds16(g + tid*16,       sWU + tid*16);
            gl_lds16(g + (tid+256)*16, sWU + (tid+256)*16);
        }
        __syncthreads();                   // drains vmcnt -> pass staged
        int ntn = (q < 2) ? 4 : 2;
        #pragma unroll
        for (int ntl = 0; ntl < ntn; ntl++) {
            int nt = q*4 + ntl;
            int n = nt*16 + lr;
            f32x4 acc = (f32x4){rbun[nt], rbun[nt], rbun[nt], rbun[nt]};
            #pragma unroll
            for (int kb = 0; kb < 4; kb++) {
                bf16x8 wu = *(const bf16x8*)(sWU + ((ntl*4 + kb)*64 + l)*16);
                acc = __builtin_amdgcn_mfma_f32_16x16x32_bf16(au[kb], wu, acc, 0, 0, 0);
            }
            if (n < 150) {
                #pragma unroll
                for (int r = 0; r < 4; r++) {
                    int rowg = tbase + quad*4 + r;
                    out[rowg*150 + n] = acc[r];
                }
            }
        }
    }
}

// ============================ launcher ======================================
extern "C" void kernel_launch(void* const* d_in, const int* in_sizes, int n_in,
                              void* d_out, int out_size, void* d_ws, size_t ws_size,
                              hipStream_t stream) {
    const int*   p_val = (const int*)d_in[0];
    const int*   a_tok = (const int*)d_in[1];
    const int*   b_tok = (const int*)d_in[2];
    const float* tok   = (const float*)d_in[3];
    const float* pos   = (const float*)d_in[4];
    const float* W_mem = (const float*)d_in[5];
    const float* b_mem = (const float*)d_in[6];
    const float* W_sur = (const float*)d_in[7];
    const float* b_sur = (const float*)d_in[8];
    const float* W_m2r = (const float*)d_in[9];
    const float* b_m2r = (const float*)d_in[10];
    const float* W_Q   = (const float*)d_in[11];
    const float* W_K   = (const float*)d_in[12];
    const float* W_V   = (const float*)d_in[13];
    const float* W_O   = (const float*)d_in[14];
    const float* W1    = (const float*)d_in[15];
    const float* b1    = (const float*)d_in[16];
    const float* W2    = (const float*)d_in[17];
    const float* b2    = (const float*)d_in[18];
    const float* WU    = (const float*)d_in[19];
    const float* bun   = (const float*)d_in[20];
    float* out = (float*)d_out;

    float* ws = (float*)d_ws;
    float* memvec = ws + OFF_MEMVEC;
    float* x3base = ws + OFF_X3BASE;
    float* KE     = ws + OFF_KE;
    float* KP     = ws + OFF_KP;
    float* SC     = ws + OFF_SC;
    __bf16* O0    = (__bf16*)(ws + OFF_O0);
    __bf16* O1    = (__bf16*)(ws + OFF_O1);
    __bf16* O2    = (__bf16*)(ws + OFF_O2);
    __bf16* O3    = (__bf16*)(ws + OFF_O3);
    __bf16* M3B   = (__bf16*)(ws + OFF_M3B);
    __bf16* W1f   = (__bf16*)(ws + OFF_W1F);
    __bf16* W2f   = (__bf16*)(ws + OFF_W2F);
    __bf16* WUf   = (__bf16*)(ws + OFF_WUF);

    k_P1a<<<307, 256, 0, stream>>>(tok, pos, W_mem, b_mem, W_sur, b_sur, W_m2r, b_m2r,
                                   W_K, memvec, x3base, KE, KP);
    k_P2x<<<825, 256, 0, stream>>>(memvec, x3base, W_Q, W_V, W_O, KE, KP,
                                   tok, pos, W1, W2, WU,
                                   SC, M3B, O0, O1, O2, O3, W1f, W2f, WUf);
    k_fused<<<NBATCH/64, 256, 0, stream>>>(p_val, a_tok, b_tok, SC, O0, O1, O2, O3, M3B,
                                           W1f, W2f, WUf, b1, b2, bun, out);
}